// Round 1
// baseline (481.299 us; speedup 1.0000x reference)
//
#include <hip/hip_runtime.h>
#include <hip/hip_bf16.h>
#include <math.h>

#define IN_DIM   128
#define OUT_DIM  64
#define THALF    64   // TIME_DIM/2
#define PE_SCALE 0.08838834764831845f  // sqrt(1/128)

// ---------------------------------------------------------------------------
// Kernel 0: tiny parameter folding.
//   aW1[k] = sum_j a[j]      * W[j][k]
//   aW2[k] = sum_j a[64+j]   * W[j][k]
//   atv[k] = sum_j a[128+j]  * Wt[j][k]
//   wvt[k][j] = Wv[j][k]   (transpose for scalar-broadcast access in k1)
// ---------------------------------------------------------------------------
__global__ void k_params(const float* __restrict__ W, const float* __restrict__ Wv,
                         const float* __restrict__ Wt, const float* __restrict__ a,
                         float* __restrict__ aW1, float* __restrict__ aW2,
                         float* __restrict__ atv, float* __restrict__ wvt)
{
    int k = threadIdx.x;                 // 0..127
    float x1 = 0.f, x2 = 0.f, x3 = 0.f;
    for (int j = 0; j < OUT_DIM; ++j) {
        float wj = W[j * IN_DIM + k];
        x1 += a[j] * wj;
        x2 += a[OUT_DIM + j] * wj;
        x3 += a[2 * OUT_DIM + j] * Wt[j * IN_DIM + k];
    }
    aW1[k] = x1; aW2[k] = x2; atv[k] = x3;
    for (int j = 0; j < OUT_DIM; ++j)
        wvt[k * OUT_DIM + j] = Wv[j * IN_DIM + k];
}

// ---------------------------------------------------------------------------
// Kernel 1: per-node projections. Work item = (node, half); each thread
// computes 32 outputs of v[n] = feats[n] @ Wv^T plus one attention scalar.
// wvt/aW accesses are wave-uniform -> scalar loads; feats via float4.
// ---------------------------------------------------------------------------
__global__ __launch_bounds__(256) void k_node_proj(
    const float* __restrict__ feats,
    const float* __restrict__ wvt,   // [128][64]
    const float* __restrict__ aW1,
    const float* __restrict__ aW2,
    float* __restrict__ v,           // [N][64]
    float* __restrict__ s1,          // [N]
    float* __restrict__ s2,          // [N]
    int N)
{
    int gid = blockIdx.x * blockDim.x + threadIdx.x;
    int n = gid >> 1;
    if (n >= N) return;
    int h = gid & 1;

    const float* aw = h ? aW2 : aW1;
    const float4* f4 = (const float4*)(feats + (size_t)n * IN_DIM);
    const float* wbase = wvt + h * 32;

    float acc[32];
#pragma unroll
    for (int j = 0; j < 32; ++j) acc[j] = 0.f;
    float sdot = 0.f;

    for (int kk = 0; kk < IN_DIM / 4; ++kk) {
        float4 f = f4[kk];
        int k = kk * 4;
        sdot += f.x * aw[k] + f.y * aw[k + 1] + f.z * aw[k + 2] + f.w * aw[k + 3];
        const float* w0 = wbase + (size_t)k * OUT_DIM;
#pragma unroll
        for (int j = 0; j < 32; ++j) {
            acc[j] += f.x * w0[j]
                    + f.y * w0[OUT_DIM + j]
                    + f.z * w0[2 * OUT_DIM + j]
                    + f.w * w0[3 * OUT_DIM + j];
        }
    }

    float* vout = v + (size_t)n * OUT_DIM + h * 32;
#pragma unroll
    for (int j = 0; j < 32; j += 4)
        *(float4*)(vout + j) = make_float4(acc[j], acc[j + 1], acc[j + 2], acc[j + 3]);

    if (h == 0) s1[n] = sdot; else s2[n] = sdot;
}

// sortable-uint encoding for float atomic max
__device__ inline unsigned f2ord(float f) {
    unsigned b = __float_as_uint(f);
    return (b & 0x80000000u) ? ~b : (b | 0x80000000u);
}
__device__ inline float ord2f(unsigned u) {
    unsigned b = (u & 0x80000000u) ? (u ^ 0x80000000u) : ~u;
    return __uint_as_float(b);
}

// ---------------------------------------------------------------------------
// Kernel 2: per-edge attention logit + segment-max via atomicMax.
//   e = s1[src] + s2[dst] + PE_SCALE * sum_i sin/cos(t*omega_i)·atv
// ---------------------------------------------------------------------------
__global__ __launch_bounds__(256) void k_edge_logits(
    const float* __restrict__ tdiff,
    const int* __restrict__ src,
    const int* __restrict__ dst,
    const float* __restrict__ omega,   // [64]
    const float* __restrict__ atv,     // [128] interleaved (sin,cos) weights
    const float* __restrict__ s1,
    const float* __restrict__ s2,
    float* __restrict__ e_val,
    unsigned* __restrict__ m_enc,
    int E)
{
    int e = blockIdx.x * blockDim.x + threadIdx.x;
    if (e >= E) return;
    float t = tdiff[e];
    int s = src[e], d = dst[e];

    float acc = 0.f;
#pragma unroll
    for (int i = 0; i < THALF; ++i) {
        float sp, cp;
        __sincosf(t * omega[i], &sp, &cp);
        acc += sp * atv[2 * i] + cp * atv[2 * i + 1];
    }
    float ev = s1[s] + s2[d] + PE_SCALE * acc;
    ev = ev > 0.f ? ev : 0.2f * ev;       // LeakyReLU(0.2)
    e_val[e] = ev;
    atomicMax(m_enc + d, f2ord(ev));
}

// ---------------------------------------------------------------------------
// Kernel 3: ex = exp(e - m[dst]); den[dst] += ex  (e_val overwritten in place)
// ---------------------------------------------------------------------------
__global__ __launch_bounds__(256) void k_edge_exp(
    const int* __restrict__ dst,
    const unsigned* __restrict__ m_enc,
    float* __restrict__ e_val,
    float* __restrict__ den,
    int E)
{
    int e = blockIdx.x * blockDim.x + threadIdx.x;
    if (e >= E) return;
    int d = dst[e];
    float ex = __expf(e_val[e] - ord2f(m_enc[d]));
    e_val[e] = ex;
    atomicAdd(den + d, ex);
}

// ---------------------------------------------------------------------------
// Kernel 4: scatter. One wave per edge: lane j handles output dim j.
//   out[dst][j] += (ex/den[dst]) * v[src][j]
// v-row gather and out-row atomics are 256B contiguous per edge.
// ---------------------------------------------------------------------------
__global__ __launch_bounds__(256) void k_scatter(
    const int* __restrict__ src,
    const int* __restrict__ dst,
    const float* __restrict__ ex,    // e_val after k3
    const float* __restrict__ den,
    const float* __restrict__ v,
    float* __restrict__ out,
    int E)
{
    long long gid = (long long)blockIdx.x * blockDim.x + threadIdx.x;
    int e = (int)(gid >> 6);
    if (e >= E) return;
    int j = (int)(gid & 63);
    int s = src[e], d = dst[e];
    float alpha = ex[e] / den[d];
    atomicAdd(out + (size_t)d * OUT_DIM + j, alpha * v[(size_t)s * OUT_DIM + j]);
}

extern "C" void kernel_launch(void* const* d_in, const int* in_sizes, int n_in,
                              void* d_out, int out_size, void* d_ws, size_t ws_size,
                              hipStream_t stream) {
    const float* feats = (const float*)d_in[0];
    const float* tdiff = (const float*)d_in[1];
    const int*   src   = (const int*)d_in[2];
    const int*   dst   = (const int*)d_in[3];
    const float* W     = (const float*)d_in[4];
    const float* Wv    = (const float*)d_in[5];
    const float* omega = (const float*)d_in[6];
    const float* Wt    = (const float*)d_in[7];
    const float* a     = (const float*)d_in[8];
    float* out = (float*)d_out;

    int N = in_sizes[0] / IN_DIM;
    int E = in_sizes[1];

    // workspace layout (floats): v | s1 | s2 | m_enc | den | e_val | params
    float*    ws    = (float*)d_ws;
    float*    v     = ws;                          // N*64
    float*    s1    = v + (size_t)N * OUT_DIM;     // N
    float*    s2    = s1 + N;                      // N
    unsigned* m_enc = (unsigned*)(s2 + N);         // N
    float*    den   = (float*)(m_enc + N);         // N
    float*    e_val = den + N;                     // E
    float*    aW1   = e_val + E;                   // 128
    float*    aW2   = aW1 + IN_DIM;                // 128
    float*    atv   = aW2 + IN_DIM;                // 128
    float*    wvt   = atv + IN_DIM;                // 128*64

    // zero the atomic targets (m_enc & den adjacent -> one memset) and output
    hipMemsetAsync(m_enc, 0, sizeof(unsigned) * (size_t)2 * N, stream);
    hipMemsetAsync(out, 0, sizeof(float) * (size_t)out_size, stream);

    k_params<<<1, 128, 0, stream>>>(W, Wv, Wt, a, aW1, aW2, atv, wvt);
    k_node_proj<<<(2 * N + 255) / 256, 256, 0, stream>>>(feats, wvt, aW1, aW2, v, s1, s2, N);
    k_edge_logits<<<(E + 255) / 256, 256, 0, stream>>>(tdiff, src, dst, omega, atv, s1, s2, e_val, m_enc, E);
    k_edge_exp<<<(E + 255) / 256, 256, 0, stream>>>(dst, m_enc, e_val, den, E);
    long long tot = (long long)E * OUT_DIM;
    k_scatter<<<(int)((tot + 255) / 256), 256, 0, stream>>>(src, dst, e_val, den, v, out, E);
}

// Round 2
// 382.237 us; speedup vs baseline: 1.2592x; 1.2592x over previous
//
#include <hip/hip_runtime.h>
#include <hip/hip_bf16.h>
#include <math.h>

#define IN_DIM   128
#define OUT_DIM  64
#define THALF    64   // TIME_DIM/2
#define PE_SCALE 0.08838834764831845f  // sqrt(1/128)

// ---------------------------------------------------------------------------
// Kernel 0: parameter folding.
//   aW1[k] = sum_j a[j]     * W[j][k]
//   aW2[k] = sum_j a[64+j]  * W[j][k]
//   atv[k] = sum_j a[128+j] * Wt[j][k]
//   wvt[k][j] = Wv[j][k]
// ---------------------------------------------------------------------------
__global__ void k_params(const float* __restrict__ W, const float* __restrict__ Wv,
                         const float* __restrict__ Wt, const float* __restrict__ a,
                         float* __restrict__ aW1, float* __restrict__ aW2,
                         float* __restrict__ atv, float* __restrict__ wvt)
{
    int k = threadIdx.x;                 // 0..127
    float x1 = 0.f, x2 = 0.f, x3 = 0.f;
    for (int j = 0; j < OUT_DIM; ++j) {
        float wj = W[j * IN_DIM + k];
        x1 += a[j] * wj;
        x2 += a[OUT_DIM + j] * wj;
        x3 += a[2 * OUT_DIM + j] * Wt[j * IN_DIM + k];
    }
    aW1[k] = x1; aW2[k] = x2; atv[k] = x3;
    for (int j = 0; j < OUT_DIM; ++j)
        wvt[k * OUT_DIM + j] = Wv[j * IN_DIM + k];
}

// ---------------------------------------------------------------------------
// Kernel 1: per-node projections. Thread = (node, half): 32 dims of
// v[n] = feats[n] @ Wv^T plus one attention scalar (s1 or s2).
// ---------------------------------------------------------------------------
__global__ __launch_bounds__(256) void k_node_proj(
    const float* __restrict__ feats,
    const float* __restrict__ wvt,   // [128][64]
    const float* __restrict__ aW1,
    const float* __restrict__ aW2,
    float* __restrict__ v,           // [N][64]
    float* __restrict__ s1,
    float* __restrict__ s2,
    int N)
{
    int gid = blockIdx.x * blockDim.x + threadIdx.x;
    int n = gid >> 1;
    if (n >= N) return;
    int h = gid & 1;

    const float* aw = h ? aW2 : aW1;
    const float4* f4 = (const float4*)(feats + (size_t)n * IN_DIM);
    const float* wbase = wvt + h * 32;

    float acc[32];
#pragma unroll
    for (int j = 0; j < 32; ++j) acc[j] = 0.f;
    float sdot = 0.f;

    for (int kk = 0; kk < IN_DIM / 4; ++kk) {
        float4 f = f4[kk];
        int k = kk * 4;
        sdot += f.x * aw[k] + f.y * aw[k + 1] + f.z * aw[k + 2] + f.w * aw[k + 3];
        const float* w0 = wbase + (size_t)k * OUT_DIM;
#pragma unroll
        for (int j = 0; j < 32; ++j) {
            acc[j] += f.x * w0[j]
                    + f.y * w0[OUT_DIM + j]
                    + f.z * w0[2 * OUT_DIM + j]
                    + f.w * w0[3 * OUT_DIM + j];
        }
    }

    float* vout = v + (size_t)n * OUT_DIM + h * 32;
#pragma unroll
    for (int j = 0; j < 32; j += 4)
        *(float4*)(vout + j) = make_float4(acc[j], acc[j + 1], acc[j + 2], acc[j + 3]);

    if (h == 0) s1[n] = sdot; else s2[n] = sdot;
}

// ---------------------------------------------------------------------------
// Kernel 2: per-edge logit e_val + per-dst edge count (for the bin sort).
// ---------------------------------------------------------------------------
__global__ __launch_bounds__(256) void k_edge_logits(
    const float* __restrict__ tdiff,
    const int* __restrict__ src,
    const int* __restrict__ dst,
    const float* __restrict__ omega,   // [64]
    const float* __restrict__ atv,     // [128] interleaved (sin,cos)
    const float* __restrict__ s1,
    const float* __restrict__ s2,
    float* __restrict__ e_val,
    int* __restrict__ cnt,
    int E)
{
    int e = blockIdx.x * blockDim.x + threadIdx.x;
    if (e >= E) return;
    float t = tdiff[e];
    int s = src[e], d = dst[e];

    float acc = 0.f;
#pragma unroll
    for (int i = 0; i < THALF; ++i) {
        float sp, cp;
        __sincosf(t * omega[i], &sp, &cp);
        acc += sp * atv[2 * i] + cp * atv[2 * i + 1];
    }
    float ev = s1[s] + s2[d] + PE_SCALE * acc;
    ev = ev > 0.f ? ev : 0.2f * ev;       // LeakyReLU(0.2)
    e_val[e] = ev;
    atomicAdd(cnt + d, 1);
}

// ---------------------------------------------------------------------------
// Scan kernels: exclusive scan of cnt[N] -> offs[N] (+ offs[N]=E), cursor copy.
// scan1: per-1024-element block partial scan; scan2: scan block sums;
// scan3: add block prefix, write cursor.
// ---------------------------------------------------------------------------
__global__ __launch_bounds__(256) void k_scan1(const int* __restrict__ cnt,
                                               int* __restrict__ offs,
                                               int* __restrict__ bsum, int N)
{
    __shared__ int lds[256];
    int b = blockIdx.x, t = threadIdx.x;
    int base = b * 1024 + t * 4;
    int v0 = (base + 0 < N) ? cnt[base + 0] : 0;
    int v1 = (base + 1 < N) ? cnt[base + 1] : 0;
    int v2 = (base + 2 < N) ? cnt[base + 2] : 0;
    int v3 = (base + 3 < N) ? cnt[base + 3] : 0;
    int s = v0 + v1 + v2 + v3;
    lds[t] = s;
    __syncthreads();
    for (int off = 1; off < 256; off <<= 1) {
        int tmp = (t >= off) ? lds[t - off] : 0;
        __syncthreads();
        lds[t] += tmp;
        __syncthreads();
    }
    int ex = lds[t] - s;  // exclusive prefix within block
    if (base + 0 < N) offs[base + 0] = ex;
    ex += v0;
    if (base + 1 < N) offs[base + 1] = ex;
    ex += v1;
    if (base + 2 < N) offs[base + 2] = ex;
    ex += v2;
    if (base + 3 < N) offs[base + 3] = ex;
    if (t == 255) bsum[b] = lds[255];
}

__global__ void k_scan2(const int* __restrict__ bsum, int* __restrict__ bpre, int nb)
{
    if (threadIdx.x == 0) {
        int run = 0;
        for (int i = 0; i < nb; ++i) { bpre[i] = run; run += bsum[i]; }
    }
}

__global__ __launch_bounds__(256) void k_scan3(int* __restrict__ offs,
                                               int* __restrict__ cursor,
                                               const int* __restrict__ bpre,
                                               int N, int E)
{
    int i = blockIdx.x * 256 + threadIdx.x;
    if (i < N) {
        int o = offs[i] + bpre[i >> 10];
        offs[i] = o;
        cursor[i] = o;
    }
    if (i == 0) offs[N] = E;
}

// ---------------------------------------------------------------------------
// Fill: perm holds edge ids grouped by dst.
// ---------------------------------------------------------------------------
__global__ __launch_bounds__(256) void k_fill(const int* __restrict__ dst,
                                              int* __restrict__ cursor,
                                              int* __restrict__ perm, int E)
{
    int e = blockIdx.x * blockDim.x + threadIdx.x;
    if (e >= E) return;
    int p = atomicAdd(cursor + dst[e], 1);
    perm[p] = e;
}

// ---------------------------------------------------------------------------
// Aggregate: one wave per node, lane = output dim. Softmax over the node's
// edges via wave reductions, then coalesced 256B v-row gathers. No atomics.
// ---------------------------------------------------------------------------
__global__ __launch_bounds__(256) void k_aggregate(
    const int* __restrict__ perm,
    const int* __restrict__ offs,
    const int* __restrict__ src,
    const float* __restrict__ e_val,
    const float* __restrict__ v,
    float* __restrict__ out,
    int N)
{
    int wid  = (blockIdx.x * blockDim.x + threadIdx.x) >> 6;
    int lane = threadIdx.x & 63;
    if (wid >= N) return;
    int beg = offs[wid], end = offs[wid + 1];
    int deg = end - beg;

    float acc = 0.f;
    if (deg > 0) {
        // pass 1: segment max
        float m = -INFINITY;
        for (int base = 0; base < deg; base += 64) {
            int i = base + lane;
            float ev = (i < deg) ? e_val[perm[beg + i]] : -INFINITY;
#pragma unroll
            for (int off = 32; off; off >>= 1)
                ev = fmaxf(ev, __shfl_xor(ev, off, 64));
            m = fmaxf(m, ev);
        }
        // pass 2: denominator
        float den = 0.f;
        for (int base = 0; base < deg; base += 64) {
            int i = base + lane;
            float ex = (i < deg) ? __expf(e_val[perm[beg + i]] - m) : 0.f;
#pragma unroll
            for (int off = 32; off; off >>= 1)
                ex += __shfl_xor(ex, off, 64);
            den += ex;  // identical on all lanes
        }
        float inv = 1.f / den;
        // pass 3: weighted accumulate (lane-parallel metadata, shfl broadcast)
        for (int base = 0; base < deg; base += 64) {
            int cl = min(64, deg - base);
            int i = base + lane;
            float al = 0.f; int sv = 0;
            if (i < deg) {
                int eid = perm[beg + i];
                al = __expf(e_val[eid] - m) * inv;
                sv = src[eid];
            }
            for (int t = 0; t < cl; ++t) {
                float a_t = __shfl(al, t, 64);
                int   s_t = __shfl(sv, t, 64);
                acc += a_t * v[(size_t)s_t * OUT_DIM + lane];
            }
        }
    }
    out[(size_t)wid * OUT_DIM + lane] = acc;
}

extern "C" void kernel_launch(void* const* d_in, const int* in_sizes, int n_in,
                              void* d_out, int out_size, void* d_ws, size_t ws_size,
                              hipStream_t stream) {
    const float* feats = (const float*)d_in[0];
    const float* tdiff = (const float*)d_in[1];
    const int*   src   = (const int*)d_in[2];
    const int*   dst   = (const int*)d_in[3];
    const float* W     = (const float*)d_in[4];
    const float* Wv    = (const float*)d_in[5];
    const float* omega = (const float*)d_in[6];
    const float* Wt    = (const float*)d_in[7];
    const float* a     = (const float*)d_in[8];
    float* out = (float*)d_out;

    int N = in_sizes[0] / IN_DIM;
    int E = in_sizes[1];

    // workspace layout (4B elements)
    float* ws     = (float*)d_ws;
    float* v      = ws;                          // N*64
    float* s1     = v + (size_t)N * OUT_DIM;     // N
    float* s2     = s1 + N;                      // N
    float* e_val  = s2 + N;                      // E
    int*   cnt    = (int*)(e_val + E);           // N
    int*   offs   = cnt + N;                     // N+1
    int*   cursor = offs + N + 1;                // N
    int*   perm   = cursor + N;                  // E
    int*   bsum   = perm + E;                    // 64
    int*   bpre   = bsum + 64;                   // 64
    float* aW1    = (float*)(bpre + 64);         // 128
    float* aW2    = aW1 + IN_DIM;                // 128
    float* atv    = aW2 + IN_DIM;                // 128
    float* wvt    = atv + IN_DIM;                // 128*64

    int nb = (N + 1023) / 1024;

    hipMemsetAsync(cnt, 0, sizeof(int) * (size_t)N, stream);

    k_params<<<1, 128, 0, stream>>>(W, Wv, Wt, a, aW1, aW2, atv, wvt);
    k_node_proj<<<(2 * N + 255) / 256, 256, 0, stream>>>(feats, wvt, aW1, aW2, v, s1, s2, N);
    k_edge_logits<<<(E + 255) / 256, 256, 0, stream>>>(tdiff, src, dst, omega, atv, s1, s2, e_val, cnt, E);
    k_scan1<<<nb, 256, 0, stream>>>(cnt, offs, bsum, N);
    k_scan2<<<1, 64, 0, stream>>>(bsum, bpre, nb);
    k_scan3<<<(N + 255) / 256, 256, 0, stream>>>(offs, cursor, bpre, N, E);
    k_fill<<<(E + 255) / 256, 256, 0, stream>>>(dst, cursor, perm, E);
    long long tot = (long long)N * OUT_DIM;
    k_aggregate<<<(int)((tot + 255) / 256), 256, 0, stream>>>(perm, offs, src, e_val, v, out, N);
}

// Round 3
// 330.097 us; speedup vs baseline: 1.4581x; 1.1580x over previous
//
#include <hip/hip_runtime.h>
#include <hip/hip_bf16.h>
#include <math.h>

#define IN_DIM   128
#define OUT_DIM  64
#define THALF    64   // TIME_DIM/2
#define PE_SCALE 0.08838834764831845f  // sqrt(1/128)

// ---------------------------------------------------------------------------
// Kernel 0: parameter folding.
//   aW1[k] = sum_j a[j]     * W[j][k]
//   aW2[k] = sum_j a[64+j]  * W[j][k]
//   atv[k] = sum_j a[128+j] * Wt[j][k]
//   wvt[k][j] = Wv[j][k]
// ---------------------------------------------------------------------------
__global__ void k_params(const float* __restrict__ W, const float* __restrict__ Wv,
                         const float* __restrict__ Wt, const float* __restrict__ a,
                         float* __restrict__ aW1, float* __restrict__ aW2,
                         float* __restrict__ atv, float* __restrict__ wvt)
{
    int k = threadIdx.x;                 // 0..127
    float x1 = 0.f, x2 = 0.f, x3 = 0.f;
    for (int j = 0; j < OUT_DIM; ++j) {
        float wj = W[j * IN_DIM + k];
        x1 += a[j] * wj;
        x2 += a[OUT_DIM + j] * wj;
        x3 += a[2 * OUT_DIM + j] * Wt[j * IN_DIM + k];
    }
    aW1[k] = x1; aW2[k] = x2; atv[k] = x3;
    for (int j = 0; j < OUT_DIM; ++j)
        wvt[k * OUT_DIM + j] = Wv[j * IN_DIM + k];
}

// ---------------------------------------------------------------------------
// Kernel 1: per-node projections. 8 threads per node, 8 output dims each.
// Grid = 8N threads -> ~24 waves/CU (was 2 threads/node -> 6 waves/CU,
// occupancy 14.8%, VALUBusy 5.5% -> latency-bound). wvt rows are L1-hot
// and wave-deduplicated; feats via float4; 8-float coalesced store.
// ---------------------------------------------------------------------------
__global__ __launch_bounds__(256) void k_node_proj(
    const float* __restrict__ feats,
    const float* __restrict__ wvt,   // [128][64]
    const float* __restrict__ aW1,
    const float* __restrict__ aW2,
    float* __restrict__ v,           // [N][64]
    float* __restrict__ s1,
    float* __restrict__ s2,
    int N)
{
    int gid = blockIdx.x * blockDim.x + threadIdx.x;
    int n = gid >> 3;
    if (n >= N) return;
    int slice = gid & 7;
    int j0 = slice * 8;

    const float* aw = (slice & 1) ? aW2 : aW1;   // only slices 0/1 store sdot
    const float4* f4 = (const float4*)(feats + (size_t)n * IN_DIM);

    float4 acc0 = make_float4(0.f, 0.f, 0.f, 0.f);
    float4 acc1 = make_float4(0.f, 0.f, 0.f, 0.f);
    float sdot = 0.f;

#pragma unroll 4
    for (int kk = 0; kk < IN_DIM / 4; ++kk) {
        float4 f = f4[kk];
        int k = kk * 4;
        sdot += f.x * aw[k] + f.y * aw[k + 1] + f.z * aw[k + 2] + f.w * aw[k + 3];
        const float* wr = wvt + (size_t)k * OUT_DIM + j0;
#pragma unroll
        for (int s = 0; s < 4; ++s) {
            float fs = (s == 0) ? f.x : (s == 1) ? f.y : (s == 2) ? f.z : f.w;
            float4 w0 = *(const float4*)(wr + (size_t)s * OUT_DIM);
            float4 w1 = *(const float4*)(wr + (size_t)s * OUT_DIM + 4);
            acc0.x += fs * w0.x; acc0.y += fs * w0.y;
            acc0.z += fs * w0.z; acc0.w += fs * w0.w;
            acc1.x += fs * w1.x; acc1.y += fs * w1.y;
            acc1.z += fs * w1.z; acc1.w += fs * w1.w;
        }
    }

    float* vout = v + (size_t)n * OUT_DIM + j0;
    *(float4*)(vout)     = acc0;
    *(float4*)(vout + 4) = acc1;

    if (slice == 0) s1[n] = sdot;
    else if (slice == 1) s2[n] = sdot;
}

// ---------------------------------------------------------------------------
// Kernel 2: per-edge logit e_val + per-dst edge count (for the bin sort).
// ---------------------------------------------------------------------------
__global__ __launch_bounds__(256) void k_edge_logits(
    const float* __restrict__ tdiff,
    const int* __restrict__ src,
    const int* __restrict__ dst,
    const float* __restrict__ omega,   // [64]
    const float* __restrict__ atv,     // [128] interleaved (sin,cos)
    const float* __restrict__ s1,
    const float* __restrict__ s2,
    float* __restrict__ e_val,
    int* __restrict__ cnt,
    int E)
{
    int e = blockIdx.x * blockDim.x + threadIdx.x;
    if (e >= E) return;
    float t = tdiff[e];
    int s = src[e], d = dst[e];

    float acc = 0.f;
#pragma unroll
    for (int i = 0; i < THALF; ++i) {
        float sp, cp;
        __sincosf(t * omega[i], &sp, &cp);
        acc += sp * atv[2 * i] + cp * atv[2 * i + 1];
    }
    float ev = s1[s] + s2[d] + PE_SCALE * acc;
    ev = ev > 0.f ? ev : 0.2f * ev;       // LeakyReLU(0.2)
    e_val[e] = ev;
    atomicAdd(cnt + d, 1);
}

// ---------------------------------------------------------------------------
// Scan kernels: exclusive scan of cnt[N] -> offs[N] (+ offs[N]=E), cursor copy.
// ---------------------------------------------------------------------------
__global__ __launch_bounds__(256) void k_scan1(const int* __restrict__ cnt,
                                               int* __restrict__ offs,
                                               int* __restrict__ bsum, int N)
{
    __shared__ int lds[256];
    int b = blockIdx.x, t = threadIdx.x;
    int base = b * 1024 + t * 4;
    int v0 = (base + 0 < N) ? cnt[base + 0] : 0;
    int v1 = (base + 1 < N) ? cnt[base + 1] : 0;
    int v2 = (base + 2 < N) ? cnt[base + 2] : 0;
    int v3 = (base + 3 < N) ? cnt[base + 3] : 0;
    int s = v0 + v1 + v2 + v3;
    lds[t] = s;
    __syncthreads();
    for (int off = 1; off < 256; off <<= 1) {
        int tmp = (t >= off) ? lds[t - off] : 0;
        __syncthreads();
        lds[t] += tmp;
        __syncthreads();
    }
    int ex = lds[t] - s;  // exclusive prefix within block
    if (base + 0 < N) offs[base + 0] = ex;
    ex += v0;
    if (base + 1 < N) offs[base + 1] = ex;
    ex += v1;
    if (base + 2 < N) offs[base + 2] = ex;
    ex += v2;
    if (base + 3 < N) offs[base + 3] = ex;
    if (t == 255) bsum[b] = lds[255];
}

__global__ void k_scan2(const int* __restrict__ bsum, int* __restrict__ bpre, int nb)
{
    if (threadIdx.x == 0) {
        int run = 0;
        for (int i = 0; i < nb; ++i) { bpre[i] = run; run += bsum[i]; }
    }
}

__global__ __launch_bounds__(256) void k_scan3(int* __restrict__ offs,
                                               int* __restrict__ cursor,
                                               const int* __restrict__ bpre,
                                               int N, int E)
{
    int i = blockIdx.x * 256 + threadIdx.x;
    if (i < N) {
        int o = offs[i] + bpre[i >> 10];
        offs[i] = o;
        cursor[i] = o;
    }
    if (i == 0) offs[N] = E;
}

// ---------------------------------------------------------------------------
// Fill: perm holds edge ids grouped by dst.
// ---------------------------------------------------------------------------
__global__ __launch_bounds__(256) void k_fill(const int* __restrict__ dst,
                                              int* __restrict__ cursor,
                                              int* __restrict__ perm, int E)
{
    int e = blockIdx.x * blockDim.x + threadIdx.x;
    if (e >= E) return;
    int p = atomicAdd(cursor + dst[e], 1);
    perm[p] = e;
}

// ---------------------------------------------------------------------------
// Aggregate: one wave per node, lane = output dim. Softmax over the node's
// edges via wave reductions, then coalesced 256B v-row gathers. No atomics.
// ---------------------------------------------------------------------------
__global__ __launch_bounds__(256) void k_aggregate(
    const int* __restrict__ perm,
    const int* __restrict__ offs,
    const int* __restrict__ src,
    const float* __restrict__ e_val,
    const float* __restrict__ v,
    float* __restrict__ out,
    int N)
{
    int wid  = (blockIdx.x * blockDim.x + threadIdx.x) >> 6;
    int lane = threadIdx.x & 63;
    if (wid >= N) return;
    int beg = offs[wid], end = offs[wid + 1];
    int deg = end - beg;

    float acc = 0.f;
    if (deg > 0) {
        // pass 1: segment max
        float m = -INFINITY;
        for (int base = 0; base < deg; base += 64) {
            int i = base + lane;
            float ev = (i < deg) ? e_val[perm[beg + i]] : -INFINITY;
#pragma unroll
            for (int off = 32; off; off >>= 1)
                ev = fmaxf(ev, __shfl_xor(ev, off, 64));
            m = fmaxf(m, ev);
        }
        // pass 2: denominator
        float den = 0.f;
        for (int base = 0; base < deg; base += 64) {
            int i = base + lane;
            float ex = (i < deg) ? __expf(e_val[perm[beg + i]] - m) : 0.f;
#pragma unroll
            for (int off = 32; off; off >>= 1)
                ex += __shfl_xor(ex, off, 64);
            den += ex;  // identical on all lanes
        }
        float inv = 1.f / den;
        // pass 3: weighted accumulate (lane-parallel metadata, shfl broadcast)
        for (int base = 0; base < deg; base += 64) {
            int cl = min(64, deg - base);
            int i = base + lane;
            float al = 0.f; int sv = 0;
            if (i < deg) {
                int eid = perm[beg + i];
                al = __expf(e_val[eid] - m) * inv;
                sv = src[eid];
            }
            for (int t = 0; t < cl; ++t) {
                float a_t = __shfl(al, t, 64);
                int   s_t = __shfl(sv, t, 64);
                acc += a_t * v[(size_t)s_t * OUT_DIM + lane];
            }
        }
    }
    out[(size_t)wid * OUT_DIM + lane] = acc;
}

extern "C" void kernel_launch(void* const* d_in, const int* in_sizes, int n_in,
                              void* d_out, int out_size, void* d_ws, size_t ws_size,
                              hipStream_t stream) {
    const float* feats = (const float*)d_in[0];
    const float* tdiff = (const float*)d_in[1];
    const int*   src   = (const int*)d_in[2];
    const int*   dst   = (const int*)d_in[3];
    const float* W     = (const float*)d_in[4];
    const float* Wv    = (const float*)d_in[5];
    const float* omega = (const float*)d_in[6];
    const float* Wt    = (const float*)d_in[7];
    const float* a     = (const float*)d_in[8];
    float* out = (float*)d_out;

    int N = in_sizes[0] / IN_DIM;
    int E = in_sizes[1];

    // workspace layout (4B elements)
    float* ws     = (float*)d_ws;
    float* v      = ws;                          // N*64
    float* s1     = v + (size_t)N * OUT_DIM;     // N
    float* s2     = s1 + N;                      // N
    float* e_val  = s2 + N;                      // E
    int*   cnt    = (int*)(e_val + E);           // N
    int*   offs   = cnt + N;                     // N+1
    int*   cursor = offs + N + 1;                // N
    int*   perm   = cursor + N;                  // E
    int*   bsum   = perm + E;                    // 64
    int*   bpre   = bsum + 64;                   // 64
    float* aW1    = (float*)(bpre + 64);         // 128
    float* aW2    = aW1 + IN_DIM;                // 128
    float* atv    = aW2 + IN_DIM;                // 128
    float* wvt    = atv + IN_DIM;                // 128*64

    int nb = (N + 1023) / 1024;

    hipMemsetAsync(cnt, 0, sizeof(int) * (size_t)N, stream);

    k_params<<<1, 128, 0, stream>>>(W, Wv, Wt, a, aW1, aW2, atv, wvt);
    k_node_proj<<<(8 * N + 255) / 256, 256, 0, stream>>>(feats, wvt, aW1, aW2, v, s1, s2, N);
    k_edge_logits<<<(E + 255) / 256, 256, 0, stream>>>(tdiff, src, dst, omega, atv, s1, s2, e_val, cnt, E);
    k_scan1<<<nb, 256, 0, stream>>>(cnt, offs, bsum, N);
    k_scan2<<<1, 64, 0, stream>>>(bsum, bpre, nb);
    k_scan3<<<(N + 255) / 256, 256, 0, stream>>>(offs, cursor, bpre, N, E);
    k_fill<<<(E + 255) / 256, 256, 0, stream>>>(dst, cursor, perm, E);
    long long tot = (long long)N * OUT_DIM;
    k_aggregate<<<(int)((tot + 255) / 256), 256, 0, stream>>>(perm, offs, src, e_val, v, out, N);
}

// Round 4
// 266.509 us; speedup vs baseline: 1.8059x; 1.2386x over previous
//
#include <hip/hip_runtime.h>
#include <hip/hip_bf16.h>
#include <math.h>

#define IN_DIM   128
#define OUT_DIM  64
#define THALF    64   // TIME_DIM/2
#define PE_SCALE 0.08838834764831845f  // sqrt(1/128)

typedef __attribute__((ext_vector_type(8))) short  short8;  // 8 bf16 (4 VGPRs)
typedef __attribute__((ext_vector_type(4))) float  f32x4;

__device__ inline unsigned short bf16_rne(float x) {
    unsigned u = __float_as_uint(x);
    return (unsigned short)((u + 0x7FFFu + ((u >> 16) & 1u)) >> 16);
}

// ---------------------------------------------------------------------------
// Kernel 0: parameter folding (128 threads, tiny).
//   aW1[k] = sum_j a[j]     * W[j][k]
//   aW2[k] = sum_j a[64+j]  * W[j][k]
//   atv[k] = sum_j a[128+j] * Wt[j][k]
// ---------------------------------------------------------------------------
__global__ void k_params(const float* __restrict__ W, const float* __restrict__ Wt,
                         const float* __restrict__ a,
                         float* __restrict__ aW1, float* __restrict__ aW2,
                         float* __restrict__ atv)
{
    int k = threadIdx.x;                 // 0..127
    float x1 = 0.f, x2 = 0.f, x3 = 0.f;
    for (int j = 0; j < OUT_DIM; ++j) {
        float wj = W[j * IN_DIM + k];
        x1 += a[j] * wj;
        x2 += a[OUT_DIM + j] * wj;
        x3 += a[2 * OUT_DIM + j] * Wt[j * IN_DIM + k];
    }
    aW1[k] = x1; aW2[k] = x2; atv[k] = x3;
}

// ---------------------------------------------------------------------------
// Kernel 0b: pack B fragments for the MFMA GEMM.
// Bp[t][k0i][lane][j] (bf16): for n-tile t<4 it's Wv[t*16+n][k] with
// n=lane&15, k=k0i*32+(lane>>4)*8+j  (mfma_f32_16x16x32_bf16 B-operand
// layout); tile t=4 carries aW1 (col 0) / aW2 (col 1), zeros elsewhere, so
// s1/s2 fall out of the same MFMA pass.
// ---------------------------------------------------------------------------
__global__ __launch_bounds__(256) void k_pack(
    const float* __restrict__ Wv,
    const float* __restrict__ aW1, const float* __restrict__ aW2,
    unsigned short* __restrict__ Bp)
{
    int i = blockIdx.x * 256 + threadIdx.x;
    if (i >= 5 * 4 * 64 * 8) return;
    int j    = i & 7;
    int lane = (i >> 3) & 63;
    int k0i  = (i >> 9) & 3;
    int t    = i >> 11;
    int k = k0i * 32 + (lane >> 4) * 8 + j;
    int n = lane & 15;
    float val;
    if (t < 4)      val = Wv[(t * 16 + n) * IN_DIM + k];
    else            val = (n == 0) ? aW1[k] : (n == 1) ? aW2[k] : 0.f;
    Bp[i] = bf16_rne(val);
}

// ---------------------------------------------------------------------------
// Kernel 1: node projection via MFMA. One wave per 16 nodes.
// A-frag: m=lane&15, k=(lane>>4)*8+j. C/D: col=lane&15, row=(lane>>4)*4+r.
// A fragments built once (f32->bf16 truncate), reused across all 5 n-tiles.
// ---------------------------------------------------------------------------
__global__ __launch_bounds__(256) void k_node_mfma(
    const float* __restrict__ feats,
    const unsigned short* __restrict__ Bp,
    float* __restrict__ v,           // [N][64]
    float* __restrict__ s1,
    float* __restrict__ s2,
    int N)
{
    int gwave = (blockIdx.x * 256 + threadIdx.x) >> 6;
    int lane  = threadIdx.x & 63;
    int ntiles = (N + 15) >> 4;
    if (gwave >= ntiles) return;
    int row = lane & 15, quad = lane >> 4;
    int nodeA = gwave * 16 + row;
    int nodeL = nodeA < N ? nodeA : N - 1;

    const float* arow = feats + (size_t)nodeL * IN_DIM + quad * 8;
    short8 afrag[4];
#pragma unroll
    for (int k0i = 0; k0i < 4; ++k0i) {
        float4 fa = *(const float4*)(arow + k0i * 32);
        float4 fb = *(const float4*)(arow + k0i * 32 + 4);
        union { unsigned u[4]; short8 s; } cv;
        cv.u[0] = (__float_as_uint(fa.x) >> 16) | (__float_as_uint(fa.y) & 0xFFFF0000u);
        cv.u[1] = (__float_as_uint(fa.z) >> 16) | (__float_as_uint(fa.w) & 0xFFFF0000u);
        cv.u[2] = (__float_as_uint(fb.x) >> 16) | (__float_as_uint(fb.y) & 0xFFFF0000u);
        cv.u[3] = (__float_as_uint(fb.z) >> 16) | (__float_as_uint(fb.w) & 0xFFFF0000u);
        afrag[k0i] = cv.s;
    }

    const short8* B8 = (const short8*)Bp;
    f32x4 acc[5];
#pragma unroll
    for (int t = 0; t < 5; ++t) acc[t] = (f32x4){0.f, 0.f, 0.f, 0.f};
#pragma unroll
    for (int t = 0; t < 5; ++t) {
#pragma unroll
        for (int k0i = 0; k0i < 4; ++k0i)
            acc[t] = __builtin_amdgcn_mfma_f32_16x16x32_bf16(
                afrag[k0i], B8[(t * 4 + k0i) * 64 + lane], acc[t], 0, 0, 0);
    }

    int col = lane & 15;
    int baseNode = gwave * 16 + quad * 4;
#pragma unroll
    for (int r = 0; r < 4; ++r) {
        int nd = baseNode + r;
        if (nd < N) {
            float* vr = v + (size_t)nd * OUT_DIM + col;
#pragma unroll
            for (int t = 0; t < 4; ++t) vr[t * 16] = acc[t][r];
            if (col == 0)      s1[nd] = acc[4][r];
            else if (col == 1) s2[nd] = acc[4][r];
        }
    }
}

// ---------------------------------------------------------------------------
// Kernel 2: per-edge logit e_val + per-dst edge count (for the bin sort).
// ---------------------------------------------------------------------------
__global__ __launch_bounds__(256) void k_edge_logits(
    const float* __restrict__ tdiff,
    const int* __restrict__ src,
    const int* __restrict__ dst,
    const float* __restrict__ omega,   // [64]
    const float* __restrict__ atv,     // [128] interleaved (sin,cos)
    const float* __restrict__ s1,
    const float* __restrict__ s2,
    float* __restrict__ e_val,
    int* __restrict__ cnt,
    int E)
{
    int e = blockIdx.x * blockDim.x + threadIdx.x;
    if (e >= E) return;
    float t = tdiff[e];
    int s = src[e], d = dst[e];

    float acc = 0.f;
#pragma unroll
    for (int i = 0; i < THALF; ++i) {
        float sp, cp;
        __sincosf(t * omega[i], &sp, &cp);
        acc += sp * atv[2 * i] + cp * atv[2 * i + 1];
    }
    float ev = s1[s] + s2[d] + PE_SCALE * acc;
    ev = ev > 0.f ? ev : 0.2f * ev;       // LeakyReLU(0.2)
    e_val[e] = ev;
    atomicAdd(cnt + d, 1);
}

// ---------------------------------------------------------------------------
// Scan kernels: exclusive scan of cnt[N] -> offs[N] (+ offs[N]=E), cursor copy.
// ---------------------------------------------------------------------------
__global__ __launch_bounds__(256) void k_scan1(const int* __restrict__ cnt,
                                               int* __restrict__ offs,
                                               int* __restrict__ bsum, int N)
{
    __shared__ int lds[256];
    int b = blockIdx.x, t = threadIdx.x;
    int base = b * 1024 + t * 4;
    int v0 = (base + 0 < N) ? cnt[base + 0] : 0;
    int v1 = (base + 1 < N) ? cnt[base + 1] : 0;
    int v2 = (base + 2 < N) ? cnt[base + 2] : 0;
    int v3 = (base + 3 < N) ? cnt[base + 3] : 0;
    int s = v0 + v1 + v2 + v3;
    lds[t] = s;
    __syncthreads();
    for (int off = 1; off < 256; off <<= 1) {
        int tmp = (t >= off) ? lds[t - off] : 0;
        __syncthreads();
        lds[t] += tmp;
        __syncthreads();
    }
    int ex = lds[t] - s;  // exclusive prefix within block
    if (base + 0 < N) offs[base + 0] = ex;
    ex += v0;
    if (base + 1 < N) offs[base + 1] = ex;
    ex += v1;
    if (base + 2 < N) offs[base + 2] = ex;
    ex += v2;
    if (base + 3 < N) offs[base + 3] = ex;
    if (t == 255) bsum[b] = lds[255];
}

__global__ void k_scan2(const int* __restrict__ bsum, int* __restrict__ bpre, int nb)
{
    if (threadIdx.x == 0) {
        int run = 0;
        for (int i = 0; i < nb; ++i) { bpre[i] = run; run += bsum[i]; }
    }
}

__global__ __launch_bounds__(256) void k_scan3(int* __restrict__ offs,
                                               int* __restrict__ cursor,
                                               const int* __restrict__ bpre,
                                               int N, int E)
{
    int i = blockIdx.x * 256 + threadIdx.x;
    if (i < N) {
        int o = offs[i] + bpre[i >> 10];
        offs[i] = o;
        cursor[i] = o;
    }
    if (i == 0) offs[N] = E;
}

// ---------------------------------------------------------------------------
// Fill: scatter edge payloads into dst-sorted order (no perm indirection
// left for the aggregate pass).
// ---------------------------------------------------------------------------
__global__ __launch_bounds__(256) void k_fill(const int* __restrict__ dst,
                                              const int* __restrict__ src,
                                              const float* __restrict__ e_val,
                                              int* __restrict__ cursor,
                                              float* __restrict__ ev_s,
                                              int* __restrict__ src_s, int E)
{
    int e = blockIdx.x * blockDim.x + threadIdx.x;
    if (e >= E) return;
    int p = atomicAdd(cursor + dst[e], 1);
    ev_s[p] = e_val[e];
    src_s[p] = src[e];
}

// ---------------------------------------------------------------------------
// Aggregate: one wave per node, lane = output dim. Coalesced reads of the
// dst-sorted ev_s/src_s; fast path (deg<=64): single gather + single exp.
// ---------------------------------------------------------------------------
__global__ __launch_bounds__(256) void k_aggregate(
    const int* __restrict__ offs,
    const float* __restrict__ ev_s,
    const int* __restrict__ src_s,
    const float* __restrict__ v,
    float* __restrict__ out,
    int N)
{
    int wid  = (blockIdx.x * blockDim.x + threadIdx.x) >> 6;
    int lane = threadIdx.x & 63;
    if (wid >= N) return;
    int beg = offs[wid];
    int deg = offs[wid + 1] - beg;

    float acc = 0.f, den = 0.f;
    if (deg > 0 && deg <= 64) {
        bool valid = lane < deg;
        float ev = valid ? ev_s[beg + lane] : -INFINITY;
        int   sv = valid ? src_s[beg + lane] : 0;
        float m = ev;
#pragma unroll
        for (int off = 32; off; off >>= 1) m = fmaxf(m, __shfl_xor(m, off, 64));
        float ex = valid ? __expf(ev - m) : 0.f;
        float sum = ex;
#pragma unroll
        for (int off = 32; off; off >>= 1) sum += __shfl_xor(sum, off, 64);
        den = sum;
        for (int t = 0; t < deg; ++t) {
            float e_t = __shfl(ex, t, 64);
            int   s_t = __shfl(sv, t, 64);
            acc += e_t * v[(size_t)s_t * OUT_DIM + lane];
        }
    } else if (deg > 0) {
        float m = -INFINITY;
        for (int base = 0; base < deg; base += 64) {
            int i = base + lane;
            float ev = (i < deg) ? ev_s[beg + i] : -INFINITY;
#pragma unroll
            for (int off = 32; off; off >>= 1) ev = fmaxf(ev, __shfl_xor(ev, off, 64));
            m = fmaxf(m, ev);
        }
        for (int base = 0; base < deg; base += 64) {
            int i = base + lane;
            float ex = (i < deg) ? __expf(ev_s[beg + i] - m) : 0.f;
#pragma unroll
            for (int off = 32; off; off >>= 1) ex += __shfl_xor(ex, off, 64);
            den += ex;
        }
        for (int base = 0; base < deg; base += 64) {
            int cl = min(64, deg - base);
            int i = base + lane;
            float ex = 0.f; int sv = 0;
            if (i < deg) {
                ex = __expf(ev_s[beg + i] - m);
                sv = src_s[beg + i];
            }
            for (int t = 0; t < cl; ++t) {
                float e_t = __shfl(ex, t, 64);
                int   s_t = __shfl(sv, t, 64);
                acc += e_t * v[(size_t)s_t * OUT_DIM + lane];
            }
        }
    }
    out[(size_t)wid * OUT_DIM + lane] = (deg > 0) ? acc / den : 0.f;
}

extern "C" void kernel_launch(void* const* d_in, const int* in_sizes, int n_in,
                              void* d_out, int out_size, void* d_ws, size_t ws_size,
                              hipStream_t stream) {
    const float* feats = (const float*)d_in[0];
    const float* tdiff = (const float*)d_in[1];
    const int*   src   = (const int*)d_in[2];
    const int*   dst   = (const int*)d_in[3];
    const float* W     = (const float*)d_in[4];
    const float* Wv    = (const float*)d_in[5];
    const float* omega = (const float*)d_in[6];
    const float* Wt    = (const float*)d_in[7];
    const float* a     = (const float*)d_in[8];
    float* out = (float*)d_out;

    int N = in_sizes[0] / IN_DIM;
    int E = in_sizes[1];

    // workspace layout (4B elements; offs padded so Bp stays 16B-aligned)
    int offs_elems = ((N + 1 + 3) / 4) * 4;
    float* ws     = (float*)d_ws;
    float* v      = ws;                          // N*64
    float* s1     = v + (size_t)N * OUT_DIM;     // N
    float* s2     = s1 + N;                      // N
    float* e_val  = s2 + N;                      // E
    float* ev_s   = e_val + E;                   // E
    int*   src_s  = (int*)(ev_s + E);            // E
    int*   cnt    = src_s + E;                   // N
    int*   offs   = cnt + N;                     // offs_elems
    int*   cursor = offs + offs_elems;           // N
    int*   bsum   = cursor + N;                  // 64
    int*   bpre   = bsum + 64;                   // 64
    float* atv    = (float*)(bpre + 64);         // 128
    float* aW1    = atv + IN_DIM;                // 128
    float* aW2    = aW1 + IN_DIM;                // 128
    unsigned short* Bp = (unsigned short*)(aW2 + IN_DIM); // 5*4*64*8 = 10240

    int nb = (N + 1023) / 1024;
    int ntiles = (N + 15) / 16;

    hipMemsetAsync(cnt, 0, sizeof(int) * (size_t)N, stream);

    k_params<<<1, 128, 0, stream>>>(W, Wt, a, aW1, aW2, atv);
    k_pack<<<(5 * 4 * 64 * 8 + 255) / 256, 256, 0, stream>>>(Wv, aW1, aW2, Bp);
    k_node_mfma<<<(ntiles * 64 + 255) / 256, 256, 0, stream>>>(feats, Bp, v, s1, s2, N);
    k_edge_logits<<<(E + 255) / 256, 256, 0, stream>>>(tdiff, src, dst, omega, atv, s1, s2, e_val, cnt, E);
    k_scan1<<<nb, 256, 0, stream>>>(cnt, offs, bsum, N);
    k_scan2<<<1, 64, 0, stream>>>(bsum, bpre, nb);
    k_scan3<<<(N + 255) / 256, 256, 0, stream>>>(offs, cursor, bpre, N, E);
    k_fill<<<(E + 255) / 256, 256, 0, stream>>>(dst, src, e_val, cursor, ev_s, src_s, E);
    long long tot = (long long)N * OUT_DIM;
    k_aggregate<<<(int)((tot + 255) / 256), 256, 0, stream>>>(offs, ev_s, src_s, v, out, N);
}

// Round 5
// 245.489 us; speedup vs baseline: 1.9606x; 1.0856x over previous
//
#include <hip/hip_runtime.h>
#include <hip/hip_bf16.h>
#include <math.h>

#define IN_DIM   128
#define OUT_DIM  64
#define THALF    64   // TIME_DIM/2
#define PE_SCALE 0.08838834764831845f  // sqrt(1/128)

typedef __attribute__((ext_vector_type(8))) short  short8;  // 8 bf16 (4 VGPRs)
typedef __attribute__((ext_vector_type(4))) float  f32x4;

__device__ inline unsigned short bf16_rne(float x) {
    unsigned u = __float_as_uint(x);
    return (unsigned short)((u + 0x7FFFu + ((u >> 16) & 1u)) >> 16);
}

// ---------------------------------------------------------------------------
// Kernel 0: parameter folding (128 threads, tiny).
//   aW1[k] = sum_j a[j]     * W[j][k]
//   aW2[k] = sum_j a[64+j]  * W[j][k]
//   atv[k] = sum_j a[128+j] * Wt[j][k]
// ---------------------------------------------------------------------------
__global__ void k_params(const float* __restrict__ W, const float* __restrict__ Wt,
                         const float* __restrict__ a,
                         float* __restrict__ aW1, float* __restrict__ aW2,
                         float* __restrict__ atv)
{
    int k = threadIdx.x;                 // 0..127
    float x1 = 0.f, x2 = 0.f, x3 = 0.f;
    for (int j = 0; j < OUT_DIM; ++j) {
        float wj = W[j * IN_DIM + k];
        x1 += a[j] * wj;
        x2 += a[OUT_DIM + j] * wj;
        x3 += a[2 * OUT_DIM + j] * Wt[j * IN_DIM + k];
    }
    aW1[k] = x1; aW2[k] = x2; atv[k] = x3;
}

// ---------------------------------------------------------------------------
// Kernel 0b: pack B fragments for the MFMA GEMM.
// Bp[t][k0i][lane][j] (bf16): n-tiles t<4 hold Wv[t*16+n][k]; tile t=4
// carries aW1 (col 0) / aW2 (col 1) so s1/s2 fall out of the same pass.
// ---------------------------------------------------------------------------
__global__ __launch_bounds__(256) void k_pack(
    const float* __restrict__ Wv,
    const float* __restrict__ aW1, const float* __restrict__ aW2,
    unsigned short* __restrict__ Bp)
{
    int i = blockIdx.x * 256 + threadIdx.x;
    if (i >= 5 * 4 * 64 * 8) return;
    int j    = i & 7;
    int lane = (i >> 3) & 63;
    int k0i  = (i >> 9) & 3;
    int t    = i >> 11;
    int k = k0i * 32 + (lane >> 4) * 8 + j;
    int n = lane & 15;
    float val;
    if (t < 4)      val = Wv[(t * 16 + n) * IN_DIM + k];
    else            val = (n == 0) ? aW1[k] : (n == 1) ? aW2[k] : 0.f;
    Bp[i] = bf16_rne(val);
}

// ---------------------------------------------------------------------------
// Kernel 1: node projection via MFMA. One wave per 16 nodes.
// ---------------------------------------------------------------------------
__global__ __launch_bounds__(256) void k_node_mfma(
    const float* __restrict__ feats,
    const unsigned short* __restrict__ Bp,
    float* __restrict__ v,           // [N][64]
    float* __restrict__ s1,
    float* __restrict__ s2,
    int N)
{
    int gwave = (blockIdx.x * 256 + threadIdx.x) >> 6;
    int lane  = threadIdx.x & 63;
    int ntiles = (N + 15) >> 4;
    if (gwave >= ntiles) return;
    int row = lane & 15, quad = lane >> 4;
    int nodeA = gwave * 16 + row;
    int nodeL = nodeA < N ? nodeA : N - 1;

    const float* arow = feats + (size_t)nodeL * IN_DIM + quad * 8;
    short8 afrag[4];
#pragma unroll
    for (int k0i = 0; k0i < 4; ++k0i) {
        float4 fa = *(const float4*)(arow + k0i * 32);
        float4 fb = *(const float4*)(arow + k0i * 32 + 4);
        union { unsigned u[4]; short8 s; } cv;
        cv.u[0] = (__float_as_uint(fa.x) >> 16) | (__float_as_uint(fa.y) & 0xFFFF0000u);
        cv.u[1] = (__float_as_uint(fa.z) >> 16) | (__float_as_uint(fa.w) & 0xFFFF0000u);
        cv.u[2] = (__float_as_uint(fb.x) >> 16) | (__float_as_uint(fb.y) & 0xFFFF0000u);
        cv.u[3] = (__float_as_uint(fb.z) >> 16) | (__float_as_uint(fb.w) & 0xFFFF0000u);
        afrag[k0i] = cv.s;
    }

    const short8* B8 = (const short8*)Bp;
    f32x4 acc[5];
#pragma unroll
    for (int t = 0; t < 5; ++t) acc[t] = (f32x4){0.f, 0.f, 0.f, 0.f};
#pragma unroll
    for (int t = 0; t < 5; ++t) {
#pragma unroll
        for (int k0i = 0; k0i < 4; ++k0i)
            acc[t] = __builtin_amdgcn_mfma_f32_16x16x32_bf16(
                afrag[k0i], B8[(t * 4 + k0i) * 64 + lane], acc[t], 0, 0, 0);
    }

    int col = lane & 15;
    int baseNode = gwave * 16 + quad * 4;
#pragma unroll
    for (int r = 0; r < 4; ++r) {
        int nd = baseNode + r;
        if (nd < N) {
            float* vr = v + (size_t)nd * OUT_DIM + col;
#pragma unroll
            for (int t = 0; t < 4; ++t) vr[t * 16] = acc[t][r];
            if (col == 0)      s1[nd] = acc[4][r];
            else if (col == 1) s2[nd] = acc[4][r];
        }
    }
}

// ---------------------------------------------------------------------------
// Kernel 2: per-dst edge count (dst-only read, atomic histogram).
// ---------------------------------------------------------------------------
__global__ __launch_bounds__(256) void k_count(const int* __restrict__ dst,
                                               int* __restrict__ cnt, int E)
{
    int e = blockIdx.x * blockDim.x + threadIdx.x;
    if (e < E) atomicAdd(cnt + dst[e], 1);
}

// ---------------------------------------------------------------------------
// Scan kernels: exclusive scan of cnt[N] -> offs[N] (+ offs[N]=E), cursor copy.
// ---------------------------------------------------------------------------
__global__ __launch_bounds__(256) void k_scan1(const int* __restrict__ cnt,
                                               int* __restrict__ offs,
                                               int* __restrict__ bsum, int N)
{
    __shared__ int lds[256];
    int b = blockIdx.x, t = threadIdx.x;
    int base = b * 1024 + t * 4;
    int v0 = (base + 0 < N) ? cnt[base + 0] : 0;
    int v1 = (base + 1 < N) ? cnt[base + 1] : 0;
    int v2 = (base + 2 < N) ? cnt[base + 2] : 0;
    int v3 = (base + 3 < N) ? cnt[base + 3] : 0;
    int s = v0 + v1 + v2 + v3;
    lds[t] = s;
    __syncthreads();
    for (int off = 1; off < 256; off <<= 1) {
        int tmp = (t >= off) ? lds[t - off] : 0;
        __syncthreads();
        lds[t] += tmp;
        __syncthreads();
    }
    int ex = lds[t] - s;  // exclusive prefix within block
    if (base + 0 < N) offs[base + 0] = ex;
    ex += v0;
    if (base + 1 < N) offs[base + 1] = ex;
    ex += v1;
    if (base + 2 < N) offs[base + 2] = ex;
    ex += v2;
    if (base + 3 < N) offs[base + 3] = ex;
    if (t == 255) bsum[b] = lds[255];
}

__global__ void k_scan2(const int* __restrict__ bsum, int* __restrict__ bpre, int nb)
{
    if (threadIdx.x == 0) {
        int run = 0;
        for (int i = 0; i < nb; ++i) { bpre[i] = run; run += bsum[i]; }
    }
}

__global__ __launch_bounds__(256) void k_scan3(int* __restrict__ offs,
                                               int* __restrict__ cursor,
                                               const int* __restrict__ bpre,
                                               int N, int E)
{
    int i = blockIdx.x * 256 + threadIdx.x;
    if (i < N) {
        int o = offs[i] + bpre[i >> 10];
        offs[i] = o;
        cursor[i] = o;
    }
    if (i == 0) offs[N] = E;
}

// ---------------------------------------------------------------------------
// Kernel 3: FUSED logits + scatter. Computes the edge logit and writes one
// 8B {ev, src} payload to its dst-sorted slot (single scattered line/edge;
// no e_val round trip, src/dst read once).
// ---------------------------------------------------------------------------
__global__ __launch_bounds__(256) void k_logits_fill(
    const float* __restrict__ tdiff,
    const int* __restrict__ src,
    const int* __restrict__ dst,
    const float* __restrict__ omega,   // [64]
    const float* __restrict__ atv,     // [128] interleaved (sin,cos)
    const float* __restrict__ s1,
    const float* __restrict__ s2,
    int* __restrict__ cursor,
    int2* __restrict__ payload,        // [E] {ev-as-bits, src}
    int E)
{
    int e = blockIdx.x * blockDim.x + threadIdx.x;
    if (e >= E) return;
    float t = tdiff[e];
    int s = src[e], d = dst[e];

    float acc = 0.f;
#pragma unroll
    for (int i = 0; i < THALF; ++i) {
        float sp, cp;
        __sincosf(t * omega[i], &sp, &cp);
        acc += sp * atv[2 * i] + cp * atv[2 * i + 1];
    }
    float ev = s1[s] + s2[d] + PE_SCALE * acc;
    ev = ev > 0.f ? ev : 0.2f * ev;       // LeakyReLU(0.2)

    int p = atomicAdd(cursor + d, 1);
    payload[p] = make_int2(__float_as_int(ev), s);
}

// ---------------------------------------------------------------------------
// Aggregate: one wave per node, lane = output dim. Coalesced int2 payload
// stream; fast path (deg<=64): single gather + single exp.
// ---------------------------------------------------------------------------
__global__ __launch_bounds__(256) void k_aggregate(
    const int* __restrict__ offs,
    const int2* __restrict__ payload,
    const float* __restrict__ v,
    float* __restrict__ out,
    int N)
{
    int wid  = (blockIdx.x * blockDim.x + threadIdx.x) >> 6;
    int lane = threadIdx.x & 63;
    if (wid >= N) return;
    int beg = offs[wid];
    int deg = offs[wid + 1] - beg;

    float acc = 0.f, den = 0.f;
    if (deg > 0 && deg <= 64) {
        bool valid = lane < deg;
        int2 pl = valid ? payload[beg + lane] : make_int2(0, 0);
        float ev = valid ? __int_as_float(pl.x) : -INFINITY;
        int   sv = pl.y;
        float m = ev;
#pragma unroll
        for (int off = 32; off; off >>= 1) m = fmaxf(m, __shfl_xor(m, off, 64));
        float ex = valid ? __expf(ev - m) : 0.f;
        float sum = ex;
#pragma unroll
        for (int off = 32; off; off >>= 1) sum += __shfl_xor(sum, off, 64);
        den = sum;
        for (int t = 0; t < deg; ++t) {
            float e_t = __shfl(ex, t, 64);
            int   s_t = __shfl(sv, t, 64);
            acc += e_t * v[(size_t)s_t * OUT_DIM + lane];
        }
    } else if (deg > 0) {
        float m = -INFINITY;
        for (int base = 0; base < deg; base += 64) {
            int i = base + lane;
            float ev = (i < deg) ? __int_as_float(payload[beg + i].x) : -INFINITY;
#pragma unroll
            for (int off = 32; off; off >>= 1) ev = fmaxf(ev, __shfl_xor(ev, off, 64));
            m = fmaxf(m, ev);
        }
        for (int base = 0; base < deg; base += 64) {
            int i = base + lane;
            float ex = (i < deg) ? __expf(__int_as_float(payload[beg + i].x) - m) : 0.f;
#pragma unroll
            for (int off = 32; off; off >>= 1) ex += __shfl_xor(ex, off, 64);
            den += ex;
        }
        for (int base = 0; base < deg; base += 64) {
            int cl = min(64, deg - base);
            int i = base + lane;
            float ex = 0.f; int sv = 0;
            if (i < deg) {
                int2 pl = payload[beg + i];
                ex = __expf(__int_as_float(pl.x) - m);
                sv = pl.y;
            }
            for (int t = 0; t < cl; ++t) {
                float e_t = __shfl(ex, t, 64);
                int   s_t = __shfl(sv, t, 64);
                acc += e_t * v[(size_t)s_t * OUT_DIM + lane];
            }
        }
    }
    out[(size_t)wid * OUT_DIM + lane] = (deg > 0) ? acc / den : 0.f;
}

extern "C" void kernel_launch(void* const* d_in, const int* in_sizes, int n_in,
                              void* d_out, int out_size, void* d_ws, size_t ws_size,
                              hipStream_t stream) {
    const float* feats = (const float*)d_in[0];
    const float* tdiff = (const float*)d_in[1];
    const int*   src   = (const int*)d_in[2];
    const int*   dst   = (const int*)d_in[3];
    const float* W     = (const float*)d_in[4];
    const float* Wv    = (const float*)d_in[5];
    const float* omega = (const float*)d_in[6];
    const float* Wt    = (const float*)d_in[7];
    const float* a     = (const float*)d_in[8];
    float* out = (float*)d_out;

    int N = in_sizes[0] / IN_DIM;
    int E = in_sizes[1];

    // workspace layout (4B elements; payload 8B-aligned: N*66 floats -> even)
    int offs_elems = ((N + 1 + 3) / 4) * 4;
    float* ws      = (float*)d_ws;
    float* v       = ws;                          // N*64
    float* s1      = v + (size_t)N * OUT_DIM;     // N
    float* s2      = s1 + N;                      // N
    int2*  payload = (int2*)(s2 + N);             // E * 8B
    int*   cnt     = (int*)(payload + E);         // N
    int*   offs    = cnt + N;                     // offs_elems
    int*   cursor  = offs + offs_elems;           // N
    int*   bsum    = cursor + N;                  // 64
    int*   bpre    = bsum + 64;                   // 64
    float* atv     = (float*)(bpre + 64);         // 128
    float* aW1     = atv + IN_DIM;                // 128
    float* aW2     = aW1 + IN_DIM;                // 128
    unsigned short* Bp = (unsigned short*)(aW2 + IN_DIM); // 5*4*64*8 = 10240

    int nb = (N + 1023) / 1024;
    int ntiles = (N + 15) / 16;

    hipMemsetAsync(cnt, 0, sizeof(int) * (size_t)N, stream);

    k_params<<<1, 128, 0, stream>>>(W, Wt, a, aW1, aW2, atv);
    k_pack<<<(5 * 4 * 64 * 8 + 255) / 256, 256, 0, stream>>>(Wv, aW1, aW2, Bp);
    k_node_mfma<<<(ntiles * 64 + 255) / 256, 256, 0, stream>>>(feats, Bp, v, s1, s2, N);
    k_count<<<(E + 255) / 256, 256, 0, stream>>>(dst, cnt, E);
    k_scan1<<<nb, 256, 0, stream>>>(cnt, offs, bsum, N);
    k_scan2<<<1, 64, 0, stream>>>(bsum, bpre, nb);
    k_scan3<<<(N + 255) / 256, 256, 0, stream>>>(offs, cursor, bpre, N, E);
    k_logits_fill<<<(E + 255) / 256, 256, 0, stream>>>(tdiff, src, dst, omega, atv, s1, s2, cursor, payload, E);
    long long tot = (long long)N * OUT_DIM;
    k_aggregate<<<(int)((tot + 255) / 256), 256, 0, stream>>>(offs, payload, v, out, N);
}